// Round 12
// baseline (173.165 us; speedup 1.0000x reference)
//
#include <hip/hip_runtime.h>
#include <math.h>

// Problem constants: N=16, V=4096, I=128, O=128, G=16
#define NN 16
#define VV 4096
#define II 128
#define OO 128
#define GG 16

typedef __attribute__((ext_vector_type(8))) short bf16x8;
typedef __attribute__((ext_vector_type(4))) float f32x4;

__device__ inline unsigned short f2bf(float f) {
    union { float f; unsigned u; } c; c.f = f;
    unsigned r = c.u + 0x7FFFu + ((c.u >> 16) & 1u);
    return (unsigned short)(r >> 16);
}
__device__ inline float bf2f(unsigned short h) {
    union { unsigned u; float f; } c; c.u = ((unsigned)h) << 16;
    return c.f;
}
__device__ inline void split1(float f, unsigned short& hi, unsigned short& lo) {
    hi = f2bf(f);
    lo = f2bf(f - bf2f(hi));
}
__device__ inline bf16x8 as_bf(uint4 u) {
    union { uint4 u; bf16x8 b; } c; c.u = u; return c.b;
}
__device__ inline void pack8(const float4& a, const float4& b, uint4& ph, uint4& pl) {
    unsigned short hi[8], lo[8];
    split1(a.x, hi[0], lo[0]); split1(a.y, hi[1], lo[1]);
    split1(a.z, hi[2], lo[2]); split1(a.w, hi[3], lo[3]);
    split1(b.x, hi[4], lo[4]); split1(b.y, hi[5], lo[5]);
    split1(b.z, hi[6], lo[6]); split1(b.w, hi[7], lo[7]);
    ph.x = (unsigned)hi[0] | ((unsigned)hi[1] << 16);
    ph.y = (unsigned)hi[2] | ((unsigned)hi[3] << 16);
    ph.z = (unsigned)hi[4] | ((unsigned)hi[5] << 16);
    ph.w = (unsigned)hi[6] | ((unsigned)hi[7] << 16);
    pl.x = (unsigned)lo[0] | ((unsigned)lo[1] << 16);
    pl.y = (unsigned)lo[2] | ((unsigned)lo[3] << 16);
    pl.z = (unsigned)lo[4] | ((unsigned)lo[5] << 16);
    pl.w = (unsigned)lo[6] | ((unsigned)lo[7] << 16);
}

#define SB() __builtin_amdgcn_sched_barrier(0)

// ---------------------------------------------------------------------------
// Pre-pack w_ih (3,G,O,I) fp32 -> split-bf16 MFMA B-fragments (HW-verified).
// pidx = (((gate*16+g)*8 + ct)*4 + s)*64 + lane; hi at wp[2*pidx], lo at +1.
// ---------------------------------------------------------------------------
__global__ __launch_bounds__(256) void prepack_kernel(
    const float* __restrict__ w_ih, uint4* __restrict__ wp)
{
    const int t  = blockIdx.x * 256 + threadIdx.x;   // [0, 98304)
    const int i8 = t & 15;
    const int o  = (t >> 4) & 127;
    const int gg = t >> 11;

    const float* src = w_ih + ((size_t)gg * OO + o) * II + i8 * 8;
    const float4 a = *(const float4*)src;
    const float4 b = *(const float4*)(src + 4);
    uint4 ph, pl;
    pack8(a, b, ph, pl);

    const int s    = i8 >> 2;
    const int kb   = i8 & 3;
    const int lane = kb * 16 + (o & 15);
    const int ct   = o >> 4;
    const int pidx = ((gg * 8 + ct) * 4 + s) * 64 + lane;
    wp[pidx * 2]     = ph;
    wp[pidx * 2 + 1] = pl;
}

// ---------------------------------------------------------------------------
// Main v3: same verified tiling as v2 (wave wv owns o-cols [wv*32,+32) of all
// 3 gates; in-register epilogue). NEW: sched_barrier(0)-fenced software
// pipeline. Half-batch = 6 loads (3 gates x hi/lo for one t column).
// A/B double buffer: issue batch in a fenced region BEFORE the fenced MFMA
// region so codegen cannot re-serialize load->use (R10 evidence: VGPR=40,
// batch deleted, 85us unchanged). Loads use pointer+=128 (2KB) per s so all
// address math stays trivial.
// ---------------------------------------------------------------------------
template <bool PREPACKED>
__global__ __launch_bounds__(256, 4) void ggru_mfma_kernel(
    const float* __restrict__ x,     // (N,V,I)
    const float* __restrict__ hx,    // (N,V,O)
    const int*   __restrict__ gidx,  // (V,)
    const uint4* __restrict__ wp,    // packed w_ih fragments
    const float* __restrict__ w_ih,  // raw (fallback)
    const float* __restrict__ b_ih,  // (3,G,O)
    const float* __restrict__ w_hh,  // (3,G,O,O)
    const float* __restrict__ b_hh,  // (3,G,O)
    float*       __restrict__ out)   // (N,V,O)
{
    const int v    = blockIdx.x;
    const int tid  = threadIdx.x;
    const int lane = tid & 63;
    const int wv   = tid >> 6;
    const int g    = gidx[v];

    __shared__ uint4 xhS[256];   // A-frags hi: idx = s*64 + lane (8 KB total)
    __shared__ uint4 xlS[256];   // A-frags lo

    // ---- stage x[:, v, :] as split-bf16 A-fragments (verified map) ----
    {
        const int row = tid >> 4;
        const int sk  = tid & 15;
        const int s   = sk >> 2, kb = sk & 3;
        const float* xp = x + ((size_t)row * VV + v) * II + s * 32 + kb * 8;
        const float4 xa = *(const float4*)xp;
        const float4 xb = *(const float4*)(xp + 4);
        uint4 ph, pl;
        pack8(xa, xb, ph, pl);
        xhS[s * 64 + kb * 16 + row] = ph;
        xlS[s * 64 + kb * 16 + row] = pl;
    }

    // ---- per-tile fragment pointers (byte step per s = 128 uint4 = 2KB) ----
    const uint4* p[3][2];
    const float* wraw[3][2];
    #pragma unroll
    for (int ga = 0; ga < 3; ++ga) {
        #pragma unroll
        for (int t = 0; t < 2; ++t) {
            const int ct = wv * 2 + t;
            p[ga][t] = wp + ((size_t)(((ga * GG + g) * 8 + ct) * 4)) * 128 + lane * 2;
            wraw[ga][t] = w_ih + (((size_t)ga * GG + g) * OO + ct * 16 + (lane & 15)) * II
                          + (lane >> 4) * 8;
        }
    }

    f32x4 acc[3][2];
    #pragma unroll
    for (int ga = 0; ga < 3; ++ga)
        #pragma unroll
        for (int t = 0; t < 2; ++t)
            acc[ga][t] = (f32x4){0.f, 0.f, 0.f, 0.f};

    uint4 A[6], B[6];   // half-batches: [2*ga]=hi, [2*ga+1]=lo

    if (PREPACKED) {
        // preload A (t=0, s=0) before the barrier: overlaps x staging
        #pragma unroll
        for (int ga = 0; ga < 3; ++ga) { A[2 * ga] = p[ga][0][0]; A[2 * ga + 1] = p[ga][0][1]; }
        SB();
        __syncthreads();

        #pragma unroll
        for (int s = 0; s < 4; ++s) {
            const bf16x8 ah = as_bf(xhS[s * 64 + lane]);
            const bf16x8 al = as_bf(xlS[s * 64 + lane]);
            // issue B batch (t=1, this s)
            #pragma unroll
            for (int ga = 0; ga < 3; ++ga) { B[2 * ga] = p[ga][1][0]; B[2 * ga + 1] = p[ga][1][1]; }
            SB();
            // MFMA on A (waits A only: counted vmcnt leaves B in flight)
            #pragma unroll
            for (int ga = 0; ga < 3; ++ga) {
                const bf16x8 wh = as_bf(A[2 * ga]);
                const bf16x8 wl = as_bf(A[2 * ga + 1]);
                acc[ga][0] = __builtin_amdgcn_mfma_f32_16x16x32_bf16(ah, wh, acc[ga][0], 0, 0, 0);
                acc[ga][0] = __builtin_amdgcn_mfma_f32_16x16x32_bf16(al, wh, acc[ga][0], 0, 0, 0);
                acc[ga][0] = __builtin_amdgcn_mfma_f32_16x16x32_bf16(ah, wl, acc[ga][0], 0, 0, 0);
            }
            SB();
            // advance t=0 pointers; issue next A (s+1)
            if (s < 3) {
                #pragma unroll
                for (int ga = 0; ga < 3; ++ga) {
                    p[ga][0] += 128;
                    A[2 * ga] = p[ga][0][0]; A[2 * ga + 1] = p[ga][0][1];
                }
                SB();
            }
            // MFMA on B
            #pragma unroll
            for (int ga = 0; ga < 3; ++ga) {
                const bf16x8 wh = as_bf(B[2 * ga]);
                const bf16x8 wl = as_bf(B[2 * ga + 1]);
                acc[ga][1] = __builtin_amdgcn_mfma_f32_16x16x32_bf16(ah, wh, acc[ga][1], 0, 0, 0);
                acc[ga][1] = __builtin_amdgcn_mfma_f32_16x16x32_bf16(al, wh, acc[ga][1], 0, 0, 0);
                acc[ga][1] = __builtin_amdgcn_mfma_f32_16x16x32_bf16(ah, wl, acc[ga][1], 0, 0, 0);
            }
            SB();
            #pragma unroll
            for (int ga = 0; ga < 3; ++ga) p[ga][1] += 128;
        }
    } else {
        __syncthreads();
        #pragma unroll
        for (int s = 0; s < 4; ++s) {
            const bf16x8 ah = as_bf(xhS[s * 64 + lane]);
            const bf16x8 al = as_bf(xlS[s * 64 + lane]);
            #pragma unroll
            for (int ga = 0; ga < 3; ++ga) {
                #pragma unroll
                for (int t = 0; t < 2; ++t) {
                    const float4 wa = *(const float4*)(wraw[ga][t] + s * 32);
                    const float4 wb = *(const float4*)(wraw[ga][t] + s * 32 + 4);
                    uint4 ph, pl;
                    pack8(wa, wb, ph, pl);
                    const bf16x8 wh = as_bf(ph);
                    const bf16x8 wl = as_bf(pl);
                    acc[ga][t] = __builtin_amdgcn_mfma_f32_16x16x32_bf16(ah, wh, acc[ga][t], 0, 0, 0);
                    acc[ga][t] = __builtin_amdgcn_mfma_f32_16x16x32_bf16(al, wh, acc[ga][t], 0, 0, 0);
                    acc[ga][t] = __builtin_amdgcn_mfma_f32_16x16x32_bf16(ah, wl, acc[ga][t], 0, 0, 0);
                }
            }
        }
    }

    // ---- in-register epilogue (verified: col=lane&15, row=(lane>>4)*4+r) ----
    const int l15 = lane & 15;
    const int rg  = lane >> 4;
    #pragma unroll
    for (int t = 0; t < 2; ++t) {
        const int o = wv * 32 + t * 16 + l15;

        const float bi0 = b_ih[(0 * GG + g) * OO + o];
        const float bi1 = b_ih[(1 * GG + g) * OO + o];
        const float bi2 = b_ih[(2 * GG + g) * OO + o];
        const float bh0 = b_hh[(0 * GG + g) * OO + o];
        const float bh1 = b_hh[(1 * GG + g) * OO + o];
        const float bh2 = b_hh[(2 * GG + g) * OO + o];
        const float wd0 = w_hh[((size_t)(0 * GG + g) * OO + o) * OO + o];
        const float wd1 = w_hh[((size_t)(1 * GG + g) * OO + o) * OO + o];
        const float wd2 = w_hh[((size_t)(2 * GG + g) * OO + o) * OO + o];

        #pragma unroll
        for (int r = 0; r < 4; ++r) {
            const int row = rg * 4 + r;
            const size_t idx = ((size_t)row * VV + v) * OO + o;
            const float h = hx[idx];

            const float gr  = acc[0][t][r] + bi0 + fmaf(h, wd0, bh0);
            const float gz  = acc[1][t][r] + bi1 + fmaf(h, wd1, bh1);
            const float ghn = fmaf(h, wd2, bh2);

            const float rr = 1.f / (1.f + __expf(-gr));
            const float zz = 1.f / (1.f + __expf(-gz));

            float tt = acc[2][t][r] + bi2 + rr * ghn;
            tt = fminf(fmaxf(tt, -15.f), 15.f);
            const float e2 = __expf(2.f * tt);
            const float th = (e2 - 1.f) / (e2 + 1.f);

            out[idx] = (1.f - zz) * th + zz * h;
        }
    }
}

extern "C" void kernel_launch(void* const* d_in, const int* in_sizes, int n_in,
                              void* d_out, int out_size, void* d_ws, size_t ws_size,
                              hipStream_t stream) {
    const float* x    = (const float*)d_in[0];
    const float* hx   = (const float*)d_in[1];
    const int*   gidx = (const int*)d_in[2];
    const float* w_ih = (const float*)d_in[3];
    const float* b_ih = (const float*)d_in[4];
    const float* w_hh = (const float*)d_in[5];
    const float* b_hh = (const float*)d_in[6];
    float* out = (float*)d_out;
    uint4* wp  = (uint4*)d_ws;   // 3 MB packed split-bf16 w_ih fragments

    const size_t need = 98304ull * 32ull;   // 3 MB
    if (ws_size >= need) {
        prepack_kernel<<<384, 256, 0, stream>>>(w_ih, wp);
        ggru_mfma_kernel<true><<<VV, 256, 0, stream>>>(
            x, hx, gidx, wp, w_ih, b_ih, w_hh, b_hh, out);
    } else {
        ggru_mfma_kernel<false><<<VV, 256, 0, stream>>>(
            x, hx, gidx, (const uint4*)nullptr, w_ih, b_ih, w_hh, b_hh, out);
    }
}

// Round 13
// 162.370 us; speedup vs baseline: 1.0665x; 1.0665x over previous
//
#include <hip/hip_runtime.h>
#include <math.h>

// Problem constants: N=16, V=4096, I=128, O=128, G=16
#define NN 16
#define VV 4096
#define II 128
#define OO 128
#define GG 16

#define VPB   4              // v's per block (same group)
#define LISTN 4144           // 4096 + 16*(VPB-1) padded worst case
#define NBLK  1036           // LISTN / VPB

typedef __attribute__((ext_vector_type(8))) short bf16x8;
typedef __attribute__((ext_vector_type(4))) float f32x4;

__device__ inline unsigned short f2bf(float f) {
    union { float f; unsigned u; } c; c.f = f;
    unsigned r = c.u + 0x7FFFu + ((c.u >> 16) & 1u);
    return (unsigned short)(r >> 16);
}
__device__ inline float bf2f(unsigned short h) {
    union { unsigned u; float f; } c; c.u = ((unsigned)h) << 16;
    return c.f;
}
__device__ inline void split1(float f, unsigned short& hi, unsigned short& lo) {
    hi = f2bf(f);
    lo = f2bf(f - bf2f(hi));
}
__device__ inline bf16x8 as_bf(uint4 u) {
    union { uint4 u; bf16x8 b; } c; c.u = u; return c.b;
}
__device__ inline void pack8(const float4& a, const float4& b, uint4& ph, uint4& pl) {
    unsigned short hi[8], lo[8];
    split1(a.x, hi[0], lo[0]); split1(a.y, hi[1], lo[1]);
    split1(a.z, hi[2], lo[2]); split1(a.w, hi[3], lo[3]);
    split1(b.x, hi[4], lo[4]); split1(b.y, hi[5], lo[5]);
    split1(b.z, hi[6], lo[6]); split1(b.w, hi[7], lo[7]);
    ph.x = (unsigned)hi[0] | ((unsigned)hi[1] << 16);
    ph.y = (unsigned)hi[2] | ((unsigned)hi[3] << 16);
    ph.z = (unsigned)hi[4] | ((unsigned)hi[5] << 16);
    ph.w = (unsigned)hi[6] | ((unsigned)hi[7] << 16);
    pl.x = (unsigned)lo[0] | ((unsigned)lo[1] << 16);
    pl.y = (unsigned)lo[2] | ((unsigned)lo[3] << 16);
    pl.z = (unsigned)lo[4] | ((unsigned)lo[5] << 16);
    pl.w = (unsigned)lo[6] | ((unsigned)lo[7] << 16);
}

// ---------------------------------------------------------------------------
// Bucket v's by group. list[LISTN]: per group, contiguous v's padded to x4
// with -1 sentinels. Single block; LDS atomics. Order within group arbitrary
// (outputs are per-v disjoint).
// ---------------------------------------------------------------------------
__global__ __launch_bounds__(256) void bucket_kernel(
    const int* __restrict__ gidx, int* __restrict__ list)
{
    __shared__ int cnt[GG], base[GG], cur[GG];
    const int tid = threadIdx.x;
    if (tid < GG) cnt[tid] = 0;
    __syncthreads();
    for (int v = tid; v < VV; v += 256) atomicAdd(&cnt[gidx[v]], 1);
    __syncthreads();
    if (tid == 0) {
        int o = 0;
        for (int g = 0; g < GG; ++g) { base[g] = o; o += (cnt[g] + VPB - 1) & ~(VPB - 1); }
    }
    __syncthreads();
    if (tid < GG) cur[tid] = base[tid];
    for (int i = tid; i < LISTN; i += 256) list[i] = -1;
    __syncthreads();
    for (int v = tid; v < VV; v += 256) {
        const int pos = atomicAdd(&cur[gidx[v]], 1);
        list[pos] = v;
    }
}

// ---------------------------------------------------------------------------
// Pre-pack w_ih (3,G,O,I) fp32 -> split-bf16 MFMA B-fragments (HW-verified
// via R6/R10/R12 passing runs). pidx = (((gate*16+g)*8+ct)*4+s)*64+lane;
// hi at wp[2*pidx], lo at wp[2*pidx+1]. 3 MB.
// ---------------------------------------------------------------------------
__global__ __launch_bounds__(256) void prepack_kernel(
    const float* __restrict__ w_ih, uint4* __restrict__ wp)
{
    const int t  = blockIdx.x * 256 + threadIdx.x;   // [0, 98304)
    const int i8 = t & 15;
    const int o  = (t >> 4) & 127;
    const int gg = t >> 11;

    const float* src = w_ih + ((size_t)gg * OO + o) * II + i8 * 8;
    const float4 a = *(const float4*)src;
    const float4 b = *(const float4*)(src + 4);
    uint4 ph, pl;
    pack8(a, b, ph, pl);

    const int s    = i8 >> 2;
    const int kb   = i8 & 3;
    const int lane = kb * 16 + (o & 15);
    const int ct   = o >> 4;
    const int pidx = ((gg * 8 + ct) * 4 + s) * 64 + lane;
    wp[pidx * 2]     = ph;
    wp[pidx * 2 + 1] = pl;
}

// ---------------------------------------------------------------------------
// Main v4: group-bucketed GEMM. Block = 4 same-group v's, 512 threads =
// 8 waves. Wave (vv = wv>>1, half = wv&1) computes, for v = vl[vv], the
// 4 ct-tiles [half*4, half*4+4) of ALL 3 gates (acc[3][4], 48 VGPR) -- so
// r/z/n for a given (row,o) stay in one lane (verified epilogue unchanged).
// Per K-step s: ALL 512 threads cooperatively stage the group's 48 KB of
// weight fragments into LDS (coalesced 32 B/thread, conflict-free ds_write),
// then waves consume via conflict-free ds_read_b128. Weight L2 traffic
// drops ~4x; serialized per-wave load chains are gone.
// ---------------------------------------------------------------------------
__global__ __launch_bounds__(512, 4) void ggru_gemm_kernel(
    const float* __restrict__ x,     // (N,V,I)
    const float* __restrict__ hx,    // (N,V,O)
    const int*   __restrict__ gidx,  // (V,)
    const uint4* __restrict__ wp,    // packed w_ih fragments
    const int*   __restrict__ list,  // bucketed v list
    const float* __restrict__ b_ih,  // (3,G,O)
    const float* __restrict__ w_hh,  // (3,G,O,O)
    const float* __restrict__ b_hh,  // (3,G,O)
    float*       __restrict__ out)   // (N,V,O)
{
    const int b    = blockIdx.x;
    const int tid  = threadIdx.x;
    const int lane = tid & 63;
    const int wv   = tid >> 6;       // 0..7
    const int vv   = wv >> 1;        // which of the 4 v's
    const int half = wv & 1;         // which half of the ct range

    const int v0 = list[b * VPB];
    if (v0 < 0) return;              // uniform: sentinel block (4-aligned regions)
    const int g = gidx[v0];

    int vl[VPB];
    #pragma unroll
    for (int k = 0; k < VPB; ++k) vl[k] = list[b * VPB + k];
    const int myv = vl[vv];

    __shared__ uint4 xhS[VPB][256];  // A-frags hi per v: idx = s*64 + lane
    __shared__ uint4 xlS[VPB][256];  // 32 KB total
    __shared__ uint4 whS[1536];      // weight hi frags for current s: (c, lane)
    __shared__ uint4 wlS[1536];      // 48 KB total

    // ---- stage x for the 4 v's (verified fragment map; coalesced 64B/thr) ----
    {
        const int tv    = tid >> 7;      // 0..3
        const int inner = tid & 127;
        const int row   = inner >> 3;    // 0..15
        const int q     = inner & 7;     // 16 floats each: i in [q*16, q*16+16)
        const int s     = q >> 1;
        const int kb0   = (q & 1) * 2;
        const int xv    = vl[tv];
        if (xv >= 0) {
            const float* xp = x + ((size_t)row * VV + xv) * II + q * 16;
            const float4 a0 = ((const float4*)xp)[0];
            const float4 a1 = ((const float4*)xp)[1];
            const float4 a2 = ((const float4*)xp)[2];
            const float4 a3 = ((const float4*)xp)[3];
            uint4 h0, l0, h1, l1;
            pack8(a0, a1, h0, l0);
            pack8(a2, a3, h1, l1);
            xhS[tv][s * 64 + kb0 * 16 + row]       = h0;
            xlS[tv][s * 64 + kb0 * 16 + row]       = l0;
            xhS[tv][s * 64 + (kb0 + 1) * 16 + row] = h1;
            xlS[tv][s * 64 + (kb0 + 1) * 16 + row] = l1;
        }
    }

    f32x4 acc[3][4];
    #pragma unroll
    for (int ga = 0; ga < 3; ++ga)
        #pragma unroll
        for (int cc = 0; cc < 4; ++cc)
            acc[ga][cc] = (f32x4){0.f, 0.f, 0.f, 0.f};

    for (int s = 0; s < 4; ++s) {
        __syncthreads();   // prev-s LDS reads done (and s=0: x writes ordered)
        // ---- cooperative weight staging: 1536 (c,lane) pairs, 3/thread ----
        #pragma unroll
        for (int j = 0; j < 3; ++j) {
            const int idx = j * 512 + tid;      // 0..1535
            const int c   = idx >> 6;           // 0..23 = ga*8 + ct
            const int l   = idx & 63;
            const int ga  = c >> 3;
            const int ct  = c & 7;
            const size_t P = ((size_t)(((ga * GG + g) * 8 + ct) * 4 + s)) * 64 + l;
            whS[idx] = wp[2 * P];
            wlS[idx] = wp[2 * P + 1];
        }
        __syncthreads();   // weights visible
        if (myv >= 0) {
            const bf16x8 ah = as_bf(xhS[vv][s * 64 + lane]);
            const bf16x8 al = as_bf(xlS[vv][s * 64 + lane]);
            #pragma unroll
            for (int ga = 0; ga < 3; ++ga) {
                #pragma unroll
                for (int cc = 0; cc < 4; ++cc) {
                    const int c = ga * 8 + half * 4 + cc;
                    const bf16x8 wh = as_bf(whS[c * 64 + lane]);
                    const bf16x8 wl = as_bf(wlS[c * 64 + lane]);
                    acc[ga][cc] = __builtin_amdgcn_mfma_f32_16x16x32_bf16(ah, wh, acc[ga][cc], 0, 0, 0);
                    acc[ga][cc] = __builtin_amdgcn_mfma_f32_16x16x32_bf16(al, wh, acc[ga][cc], 0, 0, 0);
                    acc[ga][cc] = __builtin_amdgcn_mfma_f32_16x16x32_bf16(ah, wl, acc[ga][cc], 0, 0, 0);
                }
            }
        }
    }

    if (myv < 0) return;   // sentinel waves exit after last barrier

    // ---- in-register epilogue (verified C/D map: col=lane&15, row=(lane>>4)*4+r) ----
    const int l15 = lane & 15;
    const int rg  = lane >> 4;
    #pragma unroll
    for (int cc = 0; cc < 4; ++cc) {
        const int ct = half * 4 + cc;
        const int o  = ct * 16 + l15;

        const float bi0 = b_ih[(0 * GG + g) * OO + o];
        const float bi1 = b_ih[(1 * GG + g) * OO + o];
        const float bi2 = b_ih[(2 * GG + g) * OO + o];
        const float bh0 = b_hh[(0 * GG + g) * OO + o];
        const float bh1 = b_hh[(1 * GG + g) * OO + o];
        const float bh2 = b_hh[(2 * GG + g) * OO + o];
        const float wd0 = w_hh[((size_t)(0 * GG + g) * OO + o) * OO + o];
        const float wd1 = w_hh[((size_t)(1 * GG + g) * OO + o) * OO + o];
        const float wd2 = w_hh[((size_t)(2 * GG + g) * OO + o) * OO + o];

        #pragma unroll
        for (int r = 0; r < 4; ++r) {
            const int row = rg * 4 + r;
            const size_t idx = ((size_t)row * VV + myv) * OO + o;
            const float h = hx[idx];

            const float gr  = acc[0][cc][r] + bi0 + fmaf(h, wd0, bh0);
            const float gz  = acc[1][cc][r] + bi1 + fmaf(h, wd1, bh1);
            const float ghn = fmaf(h, wd2, bh2);

            const float rr = 1.f / (1.f + __expf(-gr));
            const float zz = 1.f / (1.f + __expf(-gz));

            float tt = acc[2][cc][r] + bi2 + rr * ghn;
            tt = fminf(fmaxf(tt, -15.f), 15.f);
            const float e2 = __expf(2.f * tt);
            const float th = (e2 - 1.f) / (e2 + 1.f);

            out[idx] = (1.f - zz) * th + zz * h;
        }
    }
}

// ---------------------------------------------------------------------------
// Fallback (ws too small): per-v kernel with inline conversion (R10 v2
// structure, false path). Grid VV x 256.
// ---------------------------------------------------------------------------
__global__ __launch_bounds__(256, 4) void ggru_fallback_kernel(
    const float* __restrict__ x, const float* __restrict__ hx,
    const int* __restrict__ gidx, const float* __restrict__ w_ih,
    const float* __restrict__ b_ih, const float* __restrict__ w_hh,
    const float* __restrict__ b_hh, float* __restrict__ out)
{
    const int v    = blockIdx.x;
    const int tid  = threadIdx.x;
    const int lane = tid & 63;
    const int wv   = tid >> 6;
    const int g    = gidx[v];

    __shared__ uint4 xhS[256];
    __shared__ uint4 xlS[256];

    {
        const int row = tid >> 4;
        const int sk  = tid & 15;
        const int s   = sk >> 2, kb = sk & 3;
        const float* xp = x + ((size_t)row * VV + v) * II + s * 32 + kb * 8;
        const float4 xa = *(const float4*)xp;
        const float4 xb = *(const float4*)(xp + 4);
        uint4 ph, pl;
        pack8(xa, xb, ph, pl);
        xhS[s * 64 + kb * 16 + row] = ph;
        xlS[s * 64 + kb * 16 + row] = pl;
    }
    __syncthreads();

    const float* wraw[3][2];
    #pragma unroll
    for (int ga = 0; ga < 3; ++ga)
        #pragma unroll
        for (int t = 0; t < 2; ++t) {
            const int ct = wv * 2 + t;
            wraw[ga][t] = w_ih + (((size_t)ga * GG + g) * OO + ct * 16 + (lane & 15)) * II
                          + (lane >> 4) * 8;
        }

    f32x4 acc[3][2];
    #pragma unroll
    for (int ga = 0; ga < 3; ++ga)
        #pragma unroll
        for (int t = 0; t < 2; ++t)
            acc[ga][t] = (f32x4){0.f, 0.f, 0.f, 0.f};

    #pragma unroll
    for (int s = 0; s < 4; ++s) {
        const bf16x8 ah = as_bf(xhS[s * 64 + lane]);
        const bf16x8 al = as_bf(xlS[s * 64 + lane]);
        #pragma unroll
        for (int ga = 0; ga < 3; ++ga)
            #pragma unroll
            for (int t = 0; t < 2; ++t) {
                const float4 wa = *(const float4*)(wraw[ga][t] + s * 32);
                const float4 wb = *(const float4*)(wraw[ga][t] + s * 32 + 4);
                uint4 ph, pl;
                pack8(wa, wb, ph, pl);
                const bf16x8 wh = as_bf(ph);
                const bf16x8 wl = as_bf(pl);
                acc[ga][t] = __builtin_amdgcn_mfma_f32_16x16x32_bf16(ah, wh, acc[ga][t], 0, 0, 0);
                acc[ga][t] = __builtin_amdgcn_mfma_f32_16x16x32_bf16(al, wh, acc[ga][t], 0, 0, 0);
                acc[ga][t] = __builtin_amdgcn_mfma_f32_16x16x32_bf16(ah, wl, acc[ga][t], 0, 0, 0);
            }
    }

    const int l15 = lane & 15;
    const int rg  = lane >> 4;
    #pragma unroll
    for (int t = 0; t < 2; ++t) {
        const int o = wv * 32 + t * 16 + l15;
        const float bi0 = b_ih[(0 * GG + g) * OO + o];
        const float bi1 = b_ih[(1 * GG + g) * OO + o];
        const float bi2 = b_ih[(2 * GG + g) * OO + o];
        const float bh0 = b_hh[(0 * GG + g) * OO + o];
        const float bh1 = b_hh[(1 * GG + g) * OO + o];
        const float bh2 = b_hh[(2 * GG + g) * OO + o];
        const float wd0 = w_hh[((size_t)(0 * GG + g) * OO + o) * OO + o];
        const float wd1 = w_hh[((size_t)(1 * GG + g) * OO + o) * OO + o];
        const float wd2 = w_hh[((size_t)(2 * GG + g) * OO + o) * OO + o];
        #pragma unroll
        for (int r = 0; r < 4; ++r) {
            const int row = rg * 4 + r;
            const size_t idx = ((size_t)row * VV + v) * OO + o;
            const float h = hx[idx];
            const float gr  = acc[0][t][r] + bi0 + fmaf(h, wd0, bh0);
            const float gz  = acc[1][t][r] + bi1 + fmaf(h, wd1, bh1);
            const float ghn = fmaf(h, wd2, bh2);
            const float rr = 1.f / (1.f + __expf(-gr));
            const float zz = 1.f / (1.f + __expf(-gz));
            float tt = acc[2][t][r] + bi2 + rr * ghn;
            tt = fminf(fmaxf(tt, -15.f), 15.f);
            const float e2 = __expf(2.f * tt);
            const float th = (e2 - 1.f) / (e2 + 1.f);
            out[idx] = (1.f - zz) * th + zz * h;
        }
    }
}

extern "C" void kernel_launch(void* const* d_in, const int* in_sizes, int n_in,
                              void* d_out, int out_size, void* d_ws, size_t ws_size,
                              hipStream_t stream) {
    const float* x    = (const float*)d_in[0];
    const float* hx   = (const float*)d_in[1];
    const int*   gidx = (const int*)d_in[2];
    const float* w_ih = (const float*)d_in[3];
    const float* b_ih = (const float*)d_in[4];
    const float* w_hh = (const float*)d_in[5];
    const float* b_hh = (const float*)d_in[6];
    float* out = (float*)d_out;

    const size_t wp_bytes  = 98304ull * 32ull;            // 3 MB fragments
    const size_t need      = wp_bytes + LISTN * sizeof(int);
    uint4* wp  = (uint4*)d_ws;
    int*  list = (int*)((char*)d_ws + wp_bytes);

    if (ws_size >= need) {
        bucket_kernel<<<1, 256, 0, stream>>>(gidx, list);
        prepack_kernel<<<384, 256, 0, stream>>>(w_ih, wp);
        ggru_gemm_kernel<<<NBLK, 512, 0, stream>>>(
            x, hx, gidx, wp, list, b_ih, w_hh, b_hh, out);
    } else {
        ggru_fallback_kernel<<<VV, 256, 0, stream>>>(
            x, hx, gidx, w_ih, b_ih, w_hh, b_hh, out);
    }
}